// Round 11
// baseline (617.694 us; speedup 1.0000x reference)
//
#include <hip/hip_runtime.h>

// GRU scan: B=2048, T=2048, D=3, H=32. out[b,t] = h_new[b,t][0].
// Round-13: interleaved fused DPP-fmac + pinned 1-wave regalloc.
// R12 post-mortem: (1) VGPR_Count=96 < the 96 weight floats alone =>
// compiler reloads each asm block's weights (L1/AGPR copies) every step;
// (2) each DOT16 was a 16-deep DEPENDENT chain on one accumulator =>
// dots ran at dep rate (~4.7cy), not issue rate. Fixes:
//  - 8 asm blocks x 12 fmacs, ROUND-ROBIN over the 6 accumulators:
//    dep distance 6 >> fma latency -> issue-rate dots;
//  - __attribute__((amdgpu_waves_per_eu(1,1))): grid is 1 wave/SIMD
//    anyway; pinning it raises the VGPR budget so all 96 weights stay
//    resident (no per-step reloads). Diagnostic: VGPR_Count should jump
//    to ~200.
//  - everything else unchanged from R12 (2 seq/wave, register h, probed
//    DPP/permlane, LDS fallback).

#define GRU_B 2048
#define GRU_T 2048
#define GRU_D 3
#define GRU_H 32
#define CHUNK 32
#define XPAD 104  // seq-B x base offset (bank +8)

typedef unsigned int uint2v __attribute__((ext_vector_type(2)));

__device__ __forceinline__ float fast_sigmoid(float x) {
    float e = __expf(-x);                    // v_mul(log2e)+v_exp
    return __builtin_amdgcn_rcpf(1.0f + e);  // e=inf -> 0 (correct limit)
}
__device__ __forceinline__ float fast_tanh(float x) {
    float e = __expf(2.0f * x);              // overflow -> inf -> tanh=1
    return 1.0f - 2.0f * __builtin_amdgcn_rcpf(e + 1.0f);
}
__device__ __forceinline__ float bperm(float v, int baddr) {
    return __int_as_float(__builtin_amdgcn_ds_bpermute(baddr, __float_as_int(v)));
}

template<bool SEL>
__device__ __forceinline__ float swap32(float v) {
    uint2v r = __builtin_amdgcn_permlane32_swap(
        __float_as_uint(v), __float_as_uint(v), false, false);
    return __uint_as_float(SEL ? r.x : r.y);
}

#if __has_builtin(__builtin_amdgcn_permlane16_swap)
#define HAVE_P16 1
#else
#define HAVE_P16 0
#endif

#define S__(x) #x
#define S_(x) S__(x)

// Block 0: rotation 0 (plain fmac) + rotation 1 (dpp), round-robin 6 accs.
// s_nop 1 covers any VALU-write->DPP-read waitstates for h/hsw (cheap).
#define DOT0() \
  asm("s_nop 1\n\t" \
      "v_fmac_f32 %0, %6, %8\n\t" \
      "v_fmac_f32 %1, %6, %9\n\t" \
      "v_fmac_f32 %2, %6, %10\n\t" \
      "v_fmac_f32 %3, %7, %11\n\t" \
      "v_fmac_f32 %4, %7, %12\n\t" \
      "v_fmac_f32 %5, %7, %13\n\t" \
      "v_fmac_f32_dpp %0, %6, %14 row_ror:1 row_mask:0xf bank_mask:0xf\n\t" \
      "v_fmac_f32_dpp %1, %6, %15 row_ror:1 row_mask:0xf bank_mask:0xf\n\t" \
      "v_fmac_f32_dpp %2, %6, %16 row_ror:1 row_mask:0xf bank_mask:0xf\n\t" \
      "v_fmac_f32_dpp %3, %7, %17 row_ror:1 row_mask:0xf bank_mask:0xf\n\t" \
      "v_fmac_f32_dpp %4, %7, %18 row_ror:1 row_mask:0xf bank_mask:0xf\n\t" \
      "v_fmac_f32_dpp %5, %7, %19 row_ror:1 row_mask:0xf bank_mask:0xf" \
      : "+v"(accOr), "+v"(accOz), "+v"(accOn), \
        "+v"(accXr), "+v"(accXz), "+v"(accXn) \
      : "v"(h), "v"(hsw), \
        "v"(wrO[0]), "v"(wzO[0]), "v"(wnO[0]), \
        "v"(wrX[0]), "v"(wzX[0]), "v"(wnX[0]), \
        "v"(wrO[1]), "v"(wzO[1]), "v"(wnO[1]), \
        "v"(wrX[1]), "v"(wzX[1]), "v"(wnX[1]))

// Generic block: rotations A and B (A,B literal ints 2..15).
#define DOT12(A, B) \
  asm("v_fmac_f32_dpp %0, %6, %8  row_ror:" S_(A) " row_mask:0xf bank_mask:0xf\n\t" \
      "v_fmac_f32_dpp %1, %6, %9  row_ror:" S_(A) " row_mask:0xf bank_mask:0xf\n\t" \
      "v_fmac_f32_dpp %2, %6, %10 row_ror:" S_(A) " row_mask:0xf bank_mask:0xf\n\t" \
      "v_fmac_f32_dpp %3, %7, %11 row_ror:" S_(A) " row_mask:0xf bank_mask:0xf\n\t" \
      "v_fmac_f32_dpp %4, %7, %12 row_ror:" S_(A) " row_mask:0xf bank_mask:0xf\n\t" \
      "v_fmac_f32_dpp %5, %7, %13 row_ror:" S_(A) " row_mask:0xf bank_mask:0xf\n\t" \
      "v_fmac_f32_dpp %0, %6, %14 row_ror:" S_(B) " row_mask:0xf bank_mask:0xf\n\t" \
      "v_fmac_f32_dpp %1, %6, %15 row_ror:" S_(B) " row_mask:0xf bank_mask:0xf\n\t" \
      "v_fmac_f32_dpp %2, %6, %16 row_ror:" S_(B) " row_mask:0xf bank_mask:0xf\n\t" \
      "v_fmac_f32_dpp %3, %7, %17 row_ror:" S_(B) " row_mask:0xf bank_mask:0xf\n\t" \
      "v_fmac_f32_dpp %4, %7, %18 row_ror:" S_(B) " row_mask:0xf bank_mask:0xf\n\t" \
      "v_fmac_f32_dpp %5, %7, %19 row_ror:" S_(B) " row_mask:0xf bank_mask:0xf" \
      : "+v"(accOr), "+v"(accOz), "+v"(accOn), \
        "+v"(accXr), "+v"(accXz), "+v"(accXn) \
      : "v"(h), "v"(hsw), \
        "v"(wrO[A]), "v"(wzO[A]), "v"(wnO[A]), \
        "v"(wrX[A]), "v"(wzX[A]), "v"(wnX[A]), \
        "v"(wrO[B]), "v"(wzO[B]), "v"(wnO[B]), \
        "v"(wrX[B]), "v"(wzX[B]), "v"(wnX[B]))

// ---------------- fast path: register h, interleaved fused DPP-fmac ----------------
template<bool SEL32, bool USE16>
__device__ void gru_fast(
    const float* __restrict__ xp, float* __restrict__ ob,
    const float* __restrict__ w_ih, const float* __restrict__ w_hh,
    const float* __restrict__ bias, const float* __restrict__ bias_n,
    float* __restrict__ x_lds, int lane, int hf, int p, int dir,
    bool sel16, int a16)
{
    const int li = lane & 15;          // index within 16-row
    const int bb = 16 * (lane >> 5);   // own unit-block base (0 or 16)

    // weights permuted to rotation order: fmac j pairs row_ror:j.
    float wrO[16], wrX[16], wzO[16], wzX[16], wnO[16], wnX[16];
#pragma unroll
    for (int j = 0; j < 16; ++j) {
        const int kk = (li + dir * j + 16) & 15;
        const int kown = bb + kk;
        const int koth = (bb ^ 16) + kk;
        wrO[j] = w_hh[(size_t)p * GRU_H + kown];
        wrX[j] = w_hh[(size_t)p * GRU_H + koth];
        wzO[j] = w_hh[(size_t)(GRU_H + p) * GRU_H + kown];
        wzX[j] = w_hh[(size_t)(GRU_H + p) * GRU_H + koth];
        wnO[j] = w_hh[(size_t)(2 * GRU_H + p) * GRU_H + kown];
        wnX[j] = w_hh[(size_t)(2 * GRU_H + p) * GRU_H + koth];
    }
    float wir[GRU_D], wiz[GRU_D], win[GRU_D];
#pragma unroll
    for (int d = 0; d < GRU_D; ++d) {
        wir[d] = w_ih[(size_t)p * GRU_D + d];
        wiz[d] = w_ih[(size_t)(GRU_H + p) * GRU_D + d];
        win[d] = w_ih[(size_t)(2 * GRU_H + p) * GRU_D + d];
    }
    const float bR = bias[p];
    const float bZ = bias[GRU_H + p];
    const float bN = bias[2 * GRU_H + p] + bias_n[p];

    float* xw = x_lds + XPAD * hf;
    const float* xr = x_lds + XPAD * hf;

    float h = 0.0f;
    // global prefetch of chunk 0 (chunk-ahead; HBM-safe)
    float xa = xp[p], xb = xp[32 + p], xc = xp[64 + p];

    for (int c = 0; c < GRU_T / CHUNK; ++c) {
        // stage current chunk (regs -> LDS); prefetch next chunk (global)
        xw[p] = xa; xw[32 + p] = xb; xw[64 + p] = xc;
        if (c + 1 < GRU_T / CHUNK) {
            const size_t nb = (size_t)(c + 1) * (CHUNK * GRU_D);
            xa = xp[nb + p]; xb = xp[nb + 32 + p]; xc = xp[nb + 64 + p];
        }
        // step-0 x (ordered behind staging in the same-wave DS queue)
        float x0c = xr[0], x1c = xr[1], x2c = xr[2];
        float outreg = 0.0f;

#pragma unroll 8
        for (int s = 0; s < CHUNK; ++s) {
            // projections consume x prefetched one step ago (no stall)
            const float aR = fmaf(wir[2], x2c, fmaf(wir[1], x1c, fmaf(wir[0], x0c, bR)));
            const float aZ = fmaf(wiz[2], x2c, fmaf(wiz[1], x1c, fmaf(wiz[0], x0c, bZ)));
            const float aN = fmaf(win[2], x2c, fmaf(win[1], x1c, fmaf(win[0], x0c, bN)));

            // issue next step's x reads (consumed next iteration)
            float x0n = x0c, x1n = x1c, x2n = x2c;
            if (s + 1 < CHUNK) {
                x0n = xr[3 * (s + 1) + 0];
                x1n = xr[3 * (s + 1) + 1];
                x2n = xr[3 * (s + 1) + 2];
            }

            // one cross-block exchange; reused for hprev and the X-dots
            const float hsw = swap32<SEL32>(h);
            const float hprev = (lane & 32) ? hsw : h;

            // 96 fused fmac-dpp, round-robin across 6 accumulators
            float accOr = aR,  accXr = 0.0f;
            float accOz = aZ,  accXz = 0.0f;
            float accOn = 0.f, accXn = 0.0f;
            DOT0();
            DOT12(2, 3);
            DOT12(4, 5);
            DOT12(6, 7);
            DOT12(8, 9);
            DOT12(10, 11);
            DOT12(12, 13);
            DOT12(14, 15);

            const float rs = accOr + accXr;
            const float zs = accOz + accXz;
            const float ns = accOn + accXn;

            const float rg = fast_sigmoid(rs);
            const float zg = fast_sigmoid(zs);
            const float ng = fast_tanh(fmaf(rg, ns, aN));
            const float hnew = fmaf(zg, hprev - ng, ng);  // (1-z)*n + z*h

            // capture out[t]=h_new[t][0] (VALU broadcast, off-chain):
            // lane 0 = seq A unit 0, lane 16 = seq B unit 0.
            const float h0A = __uint_as_float(
                (unsigned)__builtin_amdgcn_readfirstlane(__float_as_int(hnew)));
            const float h0B = __uint_as_float(
                (unsigned)__builtin_amdgcn_readlane(__float_as_int(hnew), 16));
            const float want = hf ? h0B : h0A;
            if (p == s) outreg = want;

            // carry-fix: upper lanes exchange with lane^16 partner
            float fv;
            if constexpr (USE16) {
#if HAVE_P16
                uint2v f = __builtin_amdgcn_permlane16_swap(
                    __float_as_uint(hnew), __float_as_uint(hnew), false, false);
                fv = __uint_as_float(sel16 ? f.x : f.y);
#else
                fv = bperm(hnew, a16);
#endif
            } else {
                fv = bperm(hnew, a16);
            }
            h = (lane & 32) ? fv : hnew;

            x0c = x0n; x1c = x1n; x2c = x2n;
        }
        ob[c * CHUNK + p] = outreg;  // 64B runs per 16-lane group
    }
}

// ---------------- fallback: LDS h exchange (probe failure only) ----------------
__device__ void gru_lds(
    const float* __restrict__ xp, float* __restrict__ ob,
    const float* __restrict__ w_ih, const float* __restrict__ w_hh,
    const float* __restrict__ bias, const float* __restrict__ bias_n,
    float* __restrict__ x_lds, float* __restrict__ out_stage,
    float* __restrict__ h2, int lane, int hf, int p)
{
    float wr[32], wz[32], wn[32];
#pragma unroll
    for (int k = 0; k < 32; ++k) {
        wr[k] = w_hh[(size_t)p * GRU_H + k];
        wz[k] = w_hh[(size_t)(GRU_H + p) * GRU_H + k];
        wn[k] = w_hh[(size_t)(2 * GRU_H + p) * GRU_H + k];
    }
    float wir[GRU_D], wiz[GRU_D], win[GRU_D];
#pragma unroll
    for (int d = 0; d < GRU_D; ++d) {
        wir[d] = w_ih[(size_t)p * GRU_D + d];
        wiz[d] = w_ih[(size_t)(GRU_H + p) * GRU_D + d];
        win[d] = w_ih[(size_t)(2 * GRU_H + p) * GRU_D + d];
    }
    const float bR = bias[p];
    const float bZ = bias[GRU_H + p];
    const float bN = bias[2 * GRU_H + p] + bias_n[p];

    float* hw = h2 + 48 * hf + p;
    const float4* hv = (const float4*)(h2 + 48 * hf);
    float* xw = x_lds + XPAD * hf;
    const float* xr = x_lds + XPAD * hf;
    float* osw = out_stage + 32 * hf;
    const bool cap = (lane & 47) == 0;

    float h = 0.0f;
    *hw = 0.0f;
    float xa = xp[p], xb = xp[32 + p], xc = xp[64 + p];

    for (int c = 0; c < GRU_T / CHUNK; ++c) {
        xw[p] = xa; xw[32 + p] = xb; xw[64 + p] = xc;
        if (c + 1 < GRU_T / CHUNK) {
            const size_t nb = (size_t)(c + 1) * (CHUNK * GRU_D);
            xa = xp[nb + p]; xb = xp[nb + 32 + p]; xc = xp[nb + 64 + p];
        }
#pragma unroll 8
        for (int s = 0; s < CHUNK; ++s) {
            const float x0 = xr[3 * s + 0];
            const float x1 = xr[3 * s + 1];
            const float x2 = xr[3 * s + 2];
            float4 hk[8];
#pragma unroll
            for (int q = 0; q < 8; ++q) hk[q] = hv[q];

            const float aR = fmaf(wir[2], x2, fmaf(wir[1], x1, fmaf(wir[0], x0, bR)));
            const float aZ = fmaf(wiz[2], x2, fmaf(wiz[1], x1, fmaf(wiz[0], x0, bZ)));
            const float aN = fmaf(win[2], x2, fmaf(win[1], x1, fmaf(win[0], x0, bN)));

            float r0 = aR, r1 = 0.f, z0 = aZ, z1 = 0.f, n0 = 0.f, n1 = 0.f;
#pragma unroll
            for (int q = 0; q < 8; ++q) {
                const float4 v = hk[q];
                r0 = fmaf(wr[4*q+0], v.x, r0); r1 = fmaf(wr[4*q+1], v.y, r1);
                r0 = fmaf(wr[4*q+2], v.z, r0); r1 = fmaf(wr[4*q+3], v.w, r1);
                z0 = fmaf(wz[4*q+0], v.x, z0); z1 = fmaf(wz[4*q+1], v.y, z1);
                z0 = fmaf(wz[4*q+2], v.z, z0); z1 = fmaf(wz[4*q+3], v.w, z1);
                n0 = fmaf(wn[4*q+0], v.x, n0); n1 = fmaf(wn[4*q+1], v.y, n1);
                n0 = fmaf(wn[4*q+2], v.z, n0); n1 = fmaf(wn[4*q+3], v.w, n1);
            }
            const float rg = fast_sigmoid(r0 + r1);
            const float zg = fast_sigmoid(z0 + z1);
            const float ng = fast_tanh(fmaf(rg, n0 + n1, aN));
            h = fmaf(zg, h - ng, ng);
            if (cap) osw[s] = h;
            *hw = h;
        }
        const float ov = osw[p];
        ob[c * CHUNK + p] = ov;
    }
}

__global__ __launch_bounds__(64, 1)
__attribute__((amdgpu_waves_per_eu(1, 1)))
void gru_scan_kernel(
    const float* __restrict__ inp, const float* __restrict__ w_ih,
    const float* __restrict__ w_hh, const float* __restrict__ bias,
    const float* __restrict__ bias_n, float* __restrict__ out)
{
    __shared__ __align__(16) float x_lds[2 * XPAD];       // per-seq x chunk
    __shared__ __align__(16) float out_stage[2 * CHUNK];  // fallback only
    __shared__ __align__(16) float h2[80];                // fallback only

    const int lane = threadIdx.x;            // 0..63
    const int hf   = (lane >> 4) & 1;        // seq select (bit4)
    const int p    = (lane & 15) + 16 * (lane >> 5);  // owned unit / IO idx
    const size_t seq = 2 * (size_t)blockIdx.x + hf;

    const float* xp = inp + seq * (size_t)(GRU_T * GRU_D);
    float*       ob = out + seq * (size_t)GRU_T;
    const int a16 = (lane ^ 16) << 2;

    // ---- one-time probes (ballot-verified, wave-uniform) ----
    int dir = 0;
    bool ok32 = false, sel32 = false, ok16 = false, sel16 = false;
    {
        const int li = lane & 15;
        const int d1 = __builtin_amdgcn_update_dpp(0, li, 0x121, 0xF, 0xF, false);
        if (__ballot(d1 == ((li + 1) & 15)) == ~0ULL)       dir = 1;
        else if (__ballot(d1 == ((li + 15) & 15)) == ~0ULL) dir = -1;

        const unsigned ul = (unsigned)lane;
        uint2v q = __builtin_amdgcn_permlane32_swap(ul, ul, false, false);
        const unsigned w32 = ul ^ 32u;
        const bool a = __ballot(q.x == w32) == ~0ULL;
        const bool b = __ballot(q.y == w32) == ~0ULL;
        ok32 = a || b; sel32 = a;

#if HAVE_P16
        uint2v q16 = __builtin_amdgcn_permlane16_swap(ul, ul, false, false);
        const unsigned w16 = ul ^ 16u;
        const bool a16ok = __ballot(q16.x == w16) == ~0ULL;
        const bool b16ok = __ballot(q16.y == w16) == ~0ULL;
        ok16 = a16ok || b16ok; sel16 = a16ok;
#endif
    }

    if (dir != 0 && ok32) {
        if (ok16) {
            if (sel32) gru_fast<true,  true >(xp, ob, w_ih, w_hh, bias, bias_n,
                                              x_lds, lane, hf, p, dir, sel16, a16);
            else       gru_fast<false, true >(xp, ob, w_ih, w_hh, bias, bias_n,
                                              x_lds, lane, hf, p, dir, sel16, a16);
        } else {
            if (sel32) gru_fast<true,  false>(xp, ob, w_ih, w_hh, bias, bias_n,
                                              x_lds, lane, hf, p, dir, sel16, a16);
            else       gru_fast<false, false>(xp, ob, w_ih, w_hh, bias, bias_n,
                                              x_lds, lane, hf, p, dir, sel16, a16);
        }
    } else {
        gru_lds(xp, ob, w_ih, w_hh, bias, bias_n,
                x_lds, out_stage, h2, lane, hf, p);
    }
}

extern "C" void kernel_launch(void* const* d_in, const int* in_sizes, int n_in,
                              void* d_out, int out_size, void* d_ws, size_t ws_size,
                              hipStream_t stream) {
    const float* inp    = (const float*)d_in[0];
    const float* w_ih   = (const float*)d_in[1];
    const float* w_hh   = (const float*)d_in[2];
    const float* bias   = (const float*)d_in[3];
    const float* bias_n = (const float*)d_in[4];
    float* out = (float*)d_out;

    dim3 grid(GRU_B / 2);
    dim3 block(64);
    gru_scan_kernel<<<grid, block, 0, stream>>>(inp, w_ih, w_hh, bias, bias_n, out);
}